// Round 1
// baseline (1504.367 us; speedup 1.0000x reference)
//
#include <hip/hip_runtime.h>
#include <cstdint>
#include <cstddef>

// Match numpy/XLA float32 semantics: no FMA contraction anywhere.
#pragma clang fp contract(off)

#define KCLS 9
#define PRE_N 6000
#define POST_N 300
#define POOL_N 8192
#define NMS_IOU_T 0.7f
#define HIST_BLOCK 256
#define CHUNKS_PER_IMG 32
#define NMS_BLOCK 512
#define PER 12   // boxes per thread: 512*12 = 6144 >= 6000

// ---------------- stage 1: softmax over K=9 ----------------
__global__ void softmax_kernel(const float* __restrict__ labels,
                               float* __restrict__ scores, int ngroups) {
    int g = blockIdx.x * blockDim.x + threadIdx.x;
    if (g >= ngroups) return;
    const float* x = labels + (size_t)g * KCLS;
    float v[KCLS];
    float m = -1e30f;
    #pragma unroll
    for (int k = 0; k < KCLS; ++k) { v[k] = x[k]; m = fmaxf(m, v[k]); }
    float e[KCLS];
    float s = 0.f;
    #pragma unroll
    for (int k = 0; k < KCLS; ++k) { e[k] = expf(v[k] - m); s += e[k]; }
    float* o = scores + (size_t)g * KCLS;
    #pragma unroll
    for (int k = 0; k < KCLS; ++k) o[k] = e[k] / s;
}

// ---------------- stage 2a: per-pass radix histogram (full grid) ----------------
__global__ void hist_kernel(const float* __restrict__ scores,
                            unsigned int* __restrict__ ghist,        // [B][2048]
                            const unsigned int* __restrict__ state,  // [B][2] {prefix,krem}
                            int A, int shift, int bins, unsigned int pmask) {
    __shared__ unsigned int h[2048];
    const int img = blockIdx.y;
    const int chunk = blockIdx.x;
    const int tid = threadIdx.x;
    for (int i = tid; i < bins; i += HIST_BLOCK) h[i] = 0u;
    __syncthreads();
    unsigned int prefix = pmask ? (state[img * 2 + 0] & pmask) : 0u;
    const int per = A / CHUNKS_PER_IMG;
    const float* sc = scores + (size_t)img * A + (size_t)chunk * per;
    for (int i = tid; i < per; i += HIST_BLOCK) {
        unsigned int v = __float_as_uint(sc[i]);   // scores > 0: uint order == float order
        if ((v & pmask) == prefix)
            atomicAdd(&h[(v >> shift) & (unsigned)(bins - 1)], 1u);
    }
    __syncthreads();
    unsigned int* gh = ghist + (size_t)img * 2048;
    for (int i = tid; i < bins; i += HIST_BLOCK) {
        unsigned int c = h[i];
        if (c) atomicAdd(&gh[i], c);
    }
}

// ---------------- stage 2b: pick target bin (tiny, per image) ----------------
__global__ void pick_kernel(const unsigned int* __restrict__ ghist,
                            unsigned int* __restrict__ state,
                            int shift, int bins, int first_pass) {
    if (threadIdx.x != 0) return;
    const int img = blockIdx.x;
    const unsigned int* gh = ghist + (size_t)img * 2048;
    unsigned int prefix = first_pass ? 0u : state[img * 2 + 0];
    int krem = first_pass ? PRE_N : (int)state[img * 2 + 1];
    int cum = 0;
    int b = bins - 1;
    for (; b >= 0; --b) {
        int c = (int)gh[b];
        if (cum + c >= krem) break;
        cum += c;
    }
    if (b < 0) b = 0;  // safety; cannot happen
    state[img * 2 + 0] = prefix | ((unsigned int)b << shift);
    state[img * 2 + 1] = (unsigned int)(krem - cum);
}

// ---------------- stage 2c: pool build + bitonic sort + decode top-6000 ----------------
__global__ void __launch_bounds__(1024)
topk_sort_kernel(const float* __restrict__ scores,
                 const float* __restrict__ deltas,   // [B][A][4]
                 const float* __restrict__ anchors,  // [A][4]
                 const unsigned int* __restrict__ state,
                 unsigned int* __restrict__ gcnt,    // [B]
                 float* __restrict__ pre_boxes,      // [B][6000][4]
                 float* __restrict__ pre_scores,     // [B][6000]
                 int A) {
    extern __shared__ unsigned long long pool[];  // POOL_N entries = 64 KB
    const int img = blockIdx.x;
    const int tid = threadIdx.x;
    const int lane = tid & 63;
    const float* sc = scores + (size_t)img * A;
    const unsigned int T = state[img * 2 + 0];  // exact bits of the 6000th-largest score

    // pre-fill with +inf keys; pushes overwrite [0, cnt)
    for (int i = tid; i < POOL_N; i += 1024) pool[i] = ~0ull;
    __syncthreads();

    // wave-aggregated push of all scores >= T (count(>T) <= 5999, ties included)
    for (int i = tid; i < A; i += 1024) {  // A % 1024 == 0: no tail divergence
        unsigned int v = __float_as_uint(sc[i]);
        bool push = (v >= T);
        unsigned long long bal = __ballot(push ? 1 : 0);
        if (push) {
            int leader = __ffsll(bal) - 1;
            int rank = __popcll(bal & ((1ull << lane) - 1ull));
            unsigned int base = 0;
            if (lane == leader)
                base = atomicAdd(&gcnt[img], (unsigned int)__popcll(bal));
            base = (unsigned int)__shfl((int)base, leader);
            unsigned int pos = base + (unsigned int)rank;
            if (pos < POOL_N)
                pool[pos] = (((unsigned long long)(~v)) << 32) | (unsigned long long)(unsigned int)i;
        }
    }
    __syncthreads();

    // bitonic sort ascending: key = (~score_bits, index) -> score desc, index asc (top_k tie order)
    for (int k = 2; k <= POOL_N; k <<= 1) {
        for (int j = k >> 1; j > 0; j >>= 1) {
            #pragma unroll
            for (int s = 0; s < POOL_N / 1024; ++s) {
                int i = tid + s * 1024;
                int ixj = i ^ j;
                if (ixj > i) {
                    unsigned long long a = pool[i], b = pool[ixj];
                    bool up = ((i & k) == 0);
                    if ((a > b) == up) { pool[i] = b; pool[ixj] = a; }
                }
            }
            __syncthreads();
        }
    }

    // decode boxes for the top-6000 (reference float32 op order, no contraction)
    for (int r = tid; r < PRE_N; r += 1024) {
        unsigned long long key = pool[r];
        unsigned int idx = (unsigned int)(key & 0xFFFFFFFFull);
        unsigned int sbits = ~((unsigned int)(key >> 32));
        float score = __uint_as_float(sbits);
        float a0 = anchors[(size_t)idx * 4 + 0];
        float a1 = anchors[(size_t)idx * 4 + 1];
        float a2 = anchors[(size_t)idx * 4 + 2];
        float a3 = anchors[(size_t)idx * 4 + 3];
        const float* dd = deltas + ((size_t)img * A + idx) * 4;
        float d0 = dd[0] * 0.1f;
        float d1 = dd[1] * 0.1f;
        float d2 = dd[2] * 0.2f;
        float d3 = dd[3] * 0.2f;
        float anc_w = a3 - a1;
        float anc_h = a2 - a0;
        float anc_cx = a1 + 0.5f * anc_w;
        float anc_cy = a0 + 0.5f * anc_h;
        float bb_w = expf(d3) * anc_w;
        float bb_h = expf(d2) * anc_h;
        float bb_cx = d1 * anc_w + anc_cx;
        float bb_cy = d0 * anc_h + anc_cy;
        float y1 = bb_cy - 0.5f * bb_h;
        float x1 = bb_cx - 0.5f * bb_w;
        float y2 = bb_h + y1;
        float x2 = bb_w + x1;
        float* ob = pre_boxes + ((size_t)img * PRE_N + r) * 4;
        ob[0] = y1; ob[1] = x1; ob[2] = y2; ob[3] = x2;
        pre_scores[(size_t)img * PRE_N + r] = score;
    }
}

// ---------------- stage 3: greedy NMS (scores sorted => argmax == first alive) ----------------
__global__ void __launch_bounds__(NMS_BLOCK)
nms_kernel(const float* __restrict__ pre_boxes,
           const float* __restrict__ pre_scores,
           float* __restrict__ out_boxes,    // [B][300][4] (pre-zeroed)
           float* __restrict__ out_scores) { // [B][300]
    const int img = blockIdx.x;
    const int tid = threadIdx.x;
    const int lane = tid & 63;
    const int wid = tid >> 6;
    const float* bb = pre_boxes + (size_t)img * PRE_N * 4;

    float by1[PER], bx1[PER], by2[PER], bx2[PER], bar[PER];
    unsigned int alive = 0u;
    #pragma unroll
    for (int s = 0; s < PER; ++s) {
        int j = tid + s * NMS_BLOCK;
        if (j < PRE_N) {
            by1[s] = bb[j * 4 + 0];
            bx1[s] = bb[j * 4 + 1];
            by2[s] = bb[j * 4 + 2];
            bx2[s] = bb[j * 4 + 3];
            bar[s] = (by2[s] - by1[s]) * (bx2[s] - bx1[s]);
            alive |= (1u << s);
        } else {
            by1[s] = bx1[s] = by2[s] = bx2[s] = bar[s] = 0.f;
        }
    }

    __shared__ float sPiv[5];
    __shared__ int sPivIdx;
    __shared__ int sMin[NMS_BLOCK / 64];

    for (int it = 0; it < POST_N; ++it) {
        // first alive index owned by this thread (j = tid + s*NMS_BLOCK is increasing in s)
        int lm = alive ? (tid + (__ffs(alive) - 1) * NMS_BLOCK) : 0x7FFFFFFF;
        #pragma unroll
        for (int off = 32; off > 0; off >>= 1)
            lm = min(lm, __shfl_down(lm, off));
        if (lane == 0) sMin[wid] = lm;
        __syncthreads();
        if (tid == 0) {
            int m = sMin[0];
            #pragma unroll
            for (int w = 1; w < NMS_BLOCK / 64; ++w) m = min(m, sMin[w]);
            sPivIdx = (m == 0x7FFFFFFF) ? -1 : m;
        }
        __syncthreads();
        int p = sPivIdx;
        if (p < 0) break;  // all suppressed: remaining rows stay zero (valid=false)
        if (tid == (p & (NMS_BLOCK - 1))) {
            int sd = p / NMS_BLOCK;
            float py1 = 0.f, px1 = 0.f, py2 = 0.f, px2 = 0.f, pa = 0.f;
            #pragma unroll
            for (int s = 0; s < PER; ++s)
                if (s == sd) { py1 = by1[s]; px1 = bx1[s]; py2 = by2[s]; px2 = bx2[s]; pa = bar[s]; }
            sPiv[0] = py1; sPiv[1] = px1; sPiv[2] = py2; sPiv[3] = px2; sPiv[4] = pa;
            float* ob = out_boxes + ((size_t)img * POST_N + it) * 4;
            ob[0] = py1; ob[1] = px1; ob[2] = py2; ob[3] = px2;
            out_scores[(size_t)img * POST_N + it] = pre_scores[(size_t)img * PRE_N + p];
        }
        __syncthreads();
        float py1 = sPiv[0], px1 = sPiv[1], py2 = sPiv[2], px2 = sPiv[3], pa = sPiv[4];
        #pragma unroll
        for (int s = 0; s < PER; ++s) {
            if (alive & (1u << s)) {
                float iy1 = fmaxf(py1, by1[s]);
                float ix1 = fmaxf(px1, bx1[s]);
                float iy2 = fminf(py2, by2[s]);
                float ix2 = fminf(px2, bx2[s]);
                float ih = iy2 - iy1; ih = ih > 0.f ? ih : 0.f;
                float iw = ix2 - ix1; iw = iw > 0.f ? iw : 0.f;
                float inter = ih * iw;
                float iou = inter / (bar[s] + pa - inter + 1e-9f);  // ref order: (areas+b_area)-inter+eps
                if (iou > NMS_IOU_T) alive &= ~(1u << s);
            }
        }
    }
}

extern "C" void kernel_launch(void* const* d_in, const int* in_sizes, int n_in,
                              void* d_out, int out_size, void* d_ws, size_t ws_size,
                              hipStream_t stream) {
    const float* deltas  = (const float*)d_in[0];  // (B, A, 4)
    const float* labels  = (const float*)d_in[1];  // (B, FH, FW, 9)
    const float* anchors = (const float*)d_in[2];  // (A, 4)
    float* out = (float*)d_out;

    const int A = in_sizes[2] / 4;                 // 147456
    const int B = in_sizes[0] / (A * 4);           // 32
    const int ngroups = in_sizes[1] / KCLS;        // B*FH*FW

    // workspace layout
    float* scores     = (float*)d_ws;                                // B*A
    float* pre_boxes  = scores + (size_t)B * A;                      // B*6000*4
    float* pre_scores = pre_boxes + (size_t)B * PRE_N * 4;           // B*6000
    unsigned int* hist  = (unsigned int*)(pre_scores + (size_t)B * PRE_N);  // 3*B*2048
    unsigned int* state = hist + (size_t)3 * B * 2048;               // B*2
    unsigned int* gcnt  = state + (size_t)B * 2;                     // B

    float* out_boxes  = out;                        // B*300*4
    float* out_scores = out + (size_t)B * POST_N * 4;

    hipMemsetAsync(d_out, 0, (size_t)out_size * sizeof(float), stream);
    hipMemsetAsync(hist, 0, ((size_t)3 * B * 2048 + (size_t)B * 2 + (size_t)B) * sizeof(unsigned int), stream);

    softmax_kernel<<<(ngroups + 255) / 256, 256, 0, stream>>>(labels, scores, ngroups);

    dim3 hgrid(CHUNKS_PER_IMG, B);
    // pass 1: bits [31:21]
    hist_kernel<<<hgrid, HIST_BLOCK, 0, stream>>>(scores, hist + (size_t)0 * B * 2048, state, A, 21, 2048, 0x00000000u);
    pick_kernel<<<B, 64, 0, stream>>>(hist + (size_t)0 * B * 2048, state, 21, 2048, 1);
    // pass 2: bits [20:10]
    hist_kernel<<<hgrid, HIST_BLOCK, 0, stream>>>(scores, hist + (size_t)1 * B * 2048, state, A, 10, 2048, 0xFFE00000u);
    pick_kernel<<<B, 64, 0, stream>>>(hist + (size_t)1 * B * 2048, state, 10, 2048, 0);
    // pass 3: bits [9:0]
    hist_kernel<<<hgrid, HIST_BLOCK, 0, stream>>>(scores, hist + (size_t)2 * B * 2048, state, A, 0, 1024, 0xFFFFFC00u);
    pick_kernel<<<B, 64, 0, stream>>>(hist + (size_t)2 * B * 2048, state, 0, 1024, 0);

    topk_sort_kernel<<<B, 1024, POOL_N * sizeof(unsigned long long), stream>>>(
        scores, deltas, anchors, state, gcnt, pre_boxes, pre_scores, A);

    nms_kernel<<<B, NMS_BLOCK, 0, stream>>>(pre_boxes, pre_scores, out_boxes, out_scores);
}

// Round 2
// 789.238 us; speedup vs baseline: 1.9061x; 1.9061x over previous
//
#include <hip/hip_runtime.h>
#include <cstdint>
#include <cstddef>

// Match numpy/XLA float32 semantics: no FMA contraction anywhere.
#pragma clang fp contract(off)

#define KCLS 9
#define PRE_N 6000
#define POST_N 300
#define POOL_N 8192
#define NMS_IOU_T 0.7f
#define HIST_BLOCK 256
#define CHUNKS_PER_IMG 32
#define NMS_BLOCK 512
#define PER 12   // boxes per thread: 512*12 = 6144 >= 6000
#define PICK_BLOCK 256
#define IDX_INF 0x7FFFFFFF

// ---------------- stage 1: softmax over K=9 ----------------
__global__ void softmax_kernel(const float* __restrict__ labels,
                               float* __restrict__ scores, int ngroups) {
    int g = blockIdx.x * blockDim.x + threadIdx.x;
    if (g >= ngroups) return;
    const float* x = labels + (size_t)g * KCLS;
    float v[KCLS];
    float m = -1e30f;
    #pragma unroll
    for (int k = 0; k < KCLS; ++k) { v[k] = x[k]; m = fmaxf(m, v[k]); }
    float e[KCLS];
    float s = 0.f;
    #pragma unroll
    for (int k = 0; k < KCLS; ++k) { e[k] = expf(v[k] - m); s += e[k]; }
    float* o = scores + (size_t)g * KCLS;
    #pragma unroll
    for (int k = 0; k < KCLS; ++k) o[k] = e[k] / s;
}

// ---------------- stage 2a: per-pass radix histogram (full grid) ----------------
__global__ void hist_kernel(const float* __restrict__ scores,
                            unsigned int* __restrict__ ghist,        // [B][2048]
                            const unsigned int* __restrict__ state,  // [B][2] {prefix,krem}
                            int A, int shift, int bins, unsigned int pmask) {
    __shared__ unsigned int h[2048];
    const int img = blockIdx.y;
    const int chunk = blockIdx.x;
    const int tid = threadIdx.x;
    for (int i = tid; i < bins; i += HIST_BLOCK) h[i] = 0u;
    __syncthreads();
    unsigned int prefix = pmask ? (state[img * 2 + 0] & pmask) : 0u;
    const int per = A / CHUNKS_PER_IMG;
    const float* sc = scores + (size_t)img * A + (size_t)chunk * per;
    for (int i = tid; i < per; i += HIST_BLOCK) {
        unsigned int v = __float_as_uint(sc[i]);   // scores > 0: uint order == float order
        if ((v & pmask) == prefix)
            atomicAdd(&h[(v >> shift) & (unsigned)(bins - 1)], 1u);
    }
    __syncthreads();
    unsigned int* gh = ghist + (size_t)img * 2048;
    for (int i = tid; i < bins; i += HIST_BLOCK) {
        unsigned int c = h[i];
        if (c) atomicAdd(&gh[i], c);
    }
}

// ---------------- stage 2b: pick target bin (parallel suffix scan) ----------------
__global__ void __launch_bounds__(PICK_BLOCK)
pick_kernel(const unsigned int* __restrict__ ghist,
            unsigned int* __restrict__ state,
            int shift, int bins, int first_pass) {
    const int img = blockIdx.x;
    const int t = threadIdx.x;
    const unsigned int* gh = ghist + (size_t)img * 2048;
    __shared__ unsigned int cnt[2048];
    __shared__ unsigned int ssum[PICK_BLOCK];
    const int per = bins / PICK_BLOCK;   // 8 or 4
    unsigned int my = 0;
    for (int i = 0; i < per; ++i) {
        unsigned int c = gh[t * per + i];
        cnt[t * per + i] = c;
        my += c;
    }
    ssum[t] = my;
    __syncthreads();
    // inclusive suffix scan: ssum[t] = sum_{u >= t} chunk_sum[u]
    for (int d = 1; d < PICK_BLOCK; d <<= 1) {
        unsigned int v = (t + d < PICK_BLOCK) ? ssum[t + d] : 0u;
        __syncthreads();
        ssum[t] += v;
        __syncthreads();
    }
    unsigned int prefix = first_pass ? 0u : state[img * 2 + 0];
    unsigned int krem = first_pass ? (unsigned)PRE_N : state[img * 2 + 1];
    unsigned int above = ssum[t] - my;   // strictly above my chunk
    if (above < krem && ssum[t] >= krem) {   // unique thread
        unsigned int cum = above;
        for (int b = per - 1; b >= 0; --b) {
            unsigned int c = cnt[t * per + b];
            if (cum + c >= krem) {
                state[img * 2 + 0] = prefix | ((unsigned int)(t * per + b) << shift);
                state[img * 2 + 1] = krem - cum;
                break;
            }
            cum += c;
        }
    }
}

// ---------------- stage 2c: pool build + bitonic sort + decode top-6000 ----------------
__global__ void __launch_bounds__(1024)
topk_sort_kernel(const float* __restrict__ scores,
                 const float* __restrict__ deltas,   // [B][A][4]
                 const float* __restrict__ anchors,  // [A][4]
                 const unsigned int* __restrict__ state,
                 float* __restrict__ pre_boxes,      // [B][6000][4]
                 float* __restrict__ pre_scores,     // [B][6000]
                 int A) {
    extern __shared__ unsigned long long pool[];  // POOL_N entries = 64 KB
    __shared__ unsigned int cnt;                  // block-local push counter (was global)
    const int img = blockIdx.x;
    const int tid = threadIdx.x;
    const int lane = tid & 63;
    const float* sc = scores + (size_t)img * A;
    const unsigned int T = state[img * 2 + 0];  // exact bits of the 6000th-largest score

    if (tid == 0) cnt = 0u;
    // pre-fill with +inf keys; pushes overwrite [0, cnt)
    for (int i = tid; i < POOL_N; i += 1024) pool[i] = ~0ull;
    __syncthreads();

    // wave-aggregated push of all scores >= T (count(>T) <= 5999, ties included)
    for (int i = tid; i < A; i += 1024) {  // A % 1024 == 0: no tail divergence
        unsigned int v = __float_as_uint(sc[i]);
        bool push = (v >= T);
        unsigned long long bal = __ballot(push ? 1 : 0);
        if (push) {
            int leader = __ffsll(bal) - 1;
            int rank = __popcll(bal & ((1ull << lane) - 1ull));
            unsigned int base = 0;
            if (lane == leader)
                base = atomicAdd(&cnt, (unsigned int)__popcll(bal));
            base = (unsigned int)__shfl((int)base, leader);
            unsigned int pos = base + (unsigned int)rank;
            if (pos < POOL_N)
                pool[pos] = (((unsigned long long)(~v)) << 32) | (unsigned long long)(unsigned int)i;
        }
    }
    __syncthreads();

    // bitonic sort ascending: key = (~score_bits, index) -> score desc, index asc (top_k tie order)
    for (int k = 2; k <= POOL_N; k <<= 1) {
        for (int j = k >> 1; j > 0; j >>= 1) {
            #pragma unroll
            for (int s = 0; s < POOL_N / 1024; ++s) {
                int i = tid + s * 1024;
                int ixj = i ^ j;
                if (ixj > i) {
                    unsigned long long a = pool[i], b = pool[ixj];
                    bool up = ((i & k) == 0);
                    if ((a > b) == up) { pool[i] = b; pool[ixj] = a; }
                }
            }
            __syncthreads();
        }
    }

    // decode boxes for the top-6000 (reference float32 op order, no contraction)
    for (int r = tid; r < PRE_N; r += 1024) {
        unsigned long long key = pool[r];
        unsigned int idx = (unsigned int)(key & 0xFFFFFFFFull);
        unsigned int sbits = ~((unsigned int)(key >> 32));
        float score = __uint_as_float(sbits);
        float a0 = anchors[(size_t)idx * 4 + 0];
        float a1 = anchors[(size_t)idx * 4 + 1];
        float a2 = anchors[(size_t)idx * 4 + 2];
        float a3 = anchors[(size_t)idx * 4 + 3];
        const float* dd = deltas + ((size_t)img * A + idx) * 4;
        float d0 = dd[0] * 0.1f;
        float d1 = dd[1] * 0.1f;
        float d2 = dd[2] * 0.2f;
        float d3 = dd[3] * 0.2f;
        float anc_w = a3 - a1;
        float anc_h = a2 - a0;
        float anc_cx = a1 + 0.5f * anc_w;
        float anc_cy = a0 + 0.5f * anc_h;
        float bb_w = expf(d3) * anc_w;
        float bb_h = expf(d2) * anc_h;
        float bb_cx = d1 * anc_w + anc_cx;
        float bb_cy = d0 * anc_h + anc_cy;
        float y1 = bb_cy - 0.5f * bb_h;
        float x1 = bb_cx - 0.5f * bb_w;
        float y2 = bb_h + y1;
        float x2 = bb_w + x1;
        float* ob = pre_boxes + ((size_t)img * PRE_N + r) * 4;
        ob[0] = y1; ob[1] = x1; ob[2] = y2; ob[3] = x2;
        pre_scores[(size_t)img * PRE_N + r] = score;
    }
}

// ---------------- stage 3: greedy NMS (scores sorted => argmax == first alive) ----------------
// 2 barriers/iter: wave shfl-min -> LDS atomicMin (double-buffered slot),
// pivot via broadcast global float4 load. Suppression uses a multiply prescreen
// with +-1e-6 decisive margins; exact reference division only in the borderline
// window (probability ~0) -> bit-identical decisions to `inter/den > 0.7f`.
__global__ void __launch_bounds__(NMS_BLOCK)
nms_kernel(const float* __restrict__ pre_boxes,
           const float* __restrict__ pre_scores,
           float* __restrict__ out_boxes,    // [B][300][4] (pre-zeroed)
           float* __restrict__ out_scores) { // [B][300]
    const int img = blockIdx.x;
    const int tid = threadIdx.x;
    const int lane = tid & 63;
    const float4* bb4 = (const float4*)(pre_boxes + (size_t)img * PRE_N * 4);

    float by1[PER], bx1[PER], by2[PER], bx2[PER], bar[PER];
    unsigned int alive = 0u;
    #pragma unroll
    for (int s = 0; s < PER; ++s) {
        int j = tid + s * NMS_BLOCK;
        if (j < PRE_N) {
            float4 b4 = bb4[j];
            by1[s] = b4.x; bx1[s] = b4.y; by2[s] = b4.z; bx2[s] = b4.w;
            bar[s] = (b4.z - b4.x) * (b4.w - b4.y);
            alive |= (1u << s);
        } else {
            by1[s] = bx1[s] = by2[s] = bx2[s] = bar[s] = 0.f;
        }
    }

    __shared__ int slot[2];
    if (tid == 0) { slot[0] = IDX_INF; slot[1] = IDX_INF; }
    __syncthreads();

    for (int it = 0; it < POST_N; ++it) {
        const int c = it & 1;
        // first alive index owned by this thread (j = tid + s*NMS_BLOCK increases with s)
        int lm = alive ? (tid + (__ffs(alive) - 1) * NMS_BLOCK) : IDX_INF;
        #pragma unroll
        for (int off = 32; off > 0; off >>= 1)
            lm = min(lm, __shfl_down(lm, off));
        if (lane == 0 && lm != IDX_INF) atomicMin(&slot[c], lm);
        __syncthreads();                       // (B) all mins posted
        int p = slot[c];
        if (tid == 0) slot[c ^ 1] = IDX_INF;   // prep next slot (idle this window)
        __syncthreads();                       // (C) all reads done; next slot reset visible
        if (p == IDX_INF) break;               // uniform: all suppressed, rest stays zero

        float4 pb = bb4[p];                    // broadcast load (L2-resident)
        float pa = (pb.z - pb.x) * (pb.w - pb.y);  // ref: (b[2]-b[0])*(b[3]-b[1])
        if (tid == 0) {
            float* ob = out_boxes + ((size_t)img * POST_N + it) * 4;
            ob[0] = pb.x; ob[1] = pb.y; ob[2] = pb.z; ob[3] = pb.w;
            out_scores[(size_t)img * POST_N + it] = pre_scores[(size_t)img * PRE_N + p];
        }
        #pragma unroll
        for (int s = 0; s < PER; ++s) {
            float iy1 = fmaxf(pb.x, by1[s]);
            float ix1 = fmaxf(pb.y, bx1[s]);
            float iy2 = fminf(pb.z, by2[s]);
            float ix2 = fminf(pb.w, bx2[s]);
            float ih = iy2 - iy1; ih = ih > 0.f ? ih : 0.f;
            float iw = ix2 - ix1; iw = iw > 0.f ? iw : 0.f;
            float inter = ih * iw;
            float den = bar[s] + pa - inter + 1e-9f;   // ref order: ((areas+b_area)-inter)+eps
            float hi = 0.7000007f * den;               // decisive-suppress bound
            float lo = 0.6999993f * den;               // decisive-keep bound
            bool sup = inter > hi;
            if (inter >= lo && inter <= hi)            // borderline: exact reference path
                sup = (inter / den) > NMS_IOU_T;
            if (sup) alive &= ~(1u << s);
        }
    }
}

extern "C" void kernel_launch(void* const* d_in, const int* in_sizes, int n_in,
                              void* d_out, int out_size, void* d_ws, size_t ws_size,
                              hipStream_t stream) {
    const float* deltas  = (const float*)d_in[0];  // (B, A, 4)
    const float* labels  = (const float*)d_in[1];  // (B, FH, FW, 9)
    const float* anchors = (const float*)d_in[2];  // (A, 4)
    float* out = (float*)d_out;

    const int A = in_sizes[2] / 4;                 // 147456
    const int B = in_sizes[0] / (A * 4);           // 32
    const int ngroups = in_sizes[1] / KCLS;        // B*FH*FW

    // workspace layout
    float* scores     = (float*)d_ws;                                // B*A
    float* pre_boxes  = scores + (size_t)B * A;                      // B*6000*4
    float* pre_scores = pre_boxes + (size_t)B * PRE_N * 4;           // B*6000
    unsigned int* hist  = (unsigned int*)(pre_scores + (size_t)B * PRE_N);  // 3*B*2048
    unsigned int* state = hist + (size_t)3 * B * 2048;               // B*2

    float* out_boxes  = out;                        // B*300*4
    float* out_scores = out + (size_t)B * POST_N * 4;

    hipMemsetAsync(d_out, 0, (size_t)out_size * sizeof(float), stream);
    hipMemsetAsync(hist, 0, (size_t)3 * B * 2048 * sizeof(unsigned int), stream);

    softmax_kernel<<<(ngroups + 255) / 256, 256, 0, stream>>>(labels, scores, ngroups);

    dim3 hgrid(CHUNKS_PER_IMG, B);
    // pass 1: bits [31:21]
    hist_kernel<<<hgrid, HIST_BLOCK, 0, stream>>>(scores, hist + (size_t)0 * B * 2048, state, A, 21, 2048, 0x00000000u);
    pick_kernel<<<B, PICK_BLOCK, 0, stream>>>(hist + (size_t)0 * B * 2048, state, 21, 2048, 1);
    // pass 2: bits [20:10]
    hist_kernel<<<hgrid, HIST_BLOCK, 0, stream>>>(scores, hist + (size_t)1 * B * 2048, state, A, 10, 2048, 0xFFE00000u);
    pick_kernel<<<B, PICK_BLOCK, 0, stream>>>(hist + (size_t)1 * B * 2048, state, 10, 2048, 0);
    // pass 3: bits [9:0]
    hist_kernel<<<hgrid, HIST_BLOCK, 0, stream>>>(scores, hist + (size_t)2 * B * 2048, state, A, 0, 1024, 0xFFFFFC00u);
    pick_kernel<<<B, PICK_BLOCK, 0, stream>>>(hist + (size_t)2 * B * 2048, state, 0, 1024, 0);

    topk_sort_kernel<<<B, 1024, POOL_N * sizeof(unsigned long long), stream>>>(
        scores, deltas, anchors, state, pre_boxes, pre_scores, A);

    nms_kernel<<<B, NMS_BLOCK, 0, stream>>>(pre_boxes, pre_scores, out_boxes, out_scores);
}